// Round 1
// baseline (1864.819 us; speedup 1.0000x reference)
//
#include <hip/hip_runtime.h>
#include <cstdint>
#include <cmath>

typedef __bf16 bf16;
typedef __bf16 bf16x8 __attribute__((ext_vector_type(8)));
typedef __bf16 bf16x4 __attribute__((ext_vector_type(4)));
typedef float f32x4 __attribute__((ext_vector_type(4)));

#define B_ 2
#define S_ 2048
#define H_ 4096
#define NH 32
#define HD 128

__device__ __forceinline__ void gl_lds16(const void* g, void* l) {
  __builtin_amdgcn_global_load_lds(
      (const __attribute__((address_space(1))) unsigned int*)g,
      (__attribute__((address_space(3))) unsigned int*)l, 16, 0, 0);
}

// ---------------- cast f32 -> bf16 (x4 vectorized) ----------------
__global__ __launch_bounds__(256) void cast_kernel(const float* __restrict__ in,
                                                   bf16* __restrict__ out, int n4) {
  int i = blockIdx.x * 256 + threadIdx.x;
  if (i < n4) {
    float4 v = ((const float4*)in)[i];
    bf16x4 o = {(bf16)v.x, (bf16)v.y, (bf16)v.z, (bf16)v.w};
    ((bf16x4*)out)[i] = o;
  }
}

// ---------------- GEMM: C[M,N] = A[M,K] * B[N,K]^T, M=N=K=4096 ----------------
// m97 structure: 128x128 tile, BK=32, 4 waves (2x2 of 64x64), global_load_lds w=16.
// EPI 0: bf16 row-major out.  EPI 1: f32 row-major out.
template <int EPI>
__global__ __launch_bounds__(256) void gemm_bt(const bf16* __restrict__ A,
                                               const bf16* __restrict__ Bw,
                                               void* __restrict__ Cout) {
  constexpr int K = 4096, N = 4096;
  __shared__ __attribute__((aligned(16))) bf16 As[128 * 32];
  __shared__ __attribute__((aligned(16))) bf16 Bs[128 * 32];
  int tid = threadIdx.x;
  int l = tid & 63;
  int lr = l & 15, lg = l >> 4;
  int w = tid >> 6;
  int wr = (w >> 1) * 64, wc = (w & 1) * 64;
  int r0 = blockIdx.x * 128, c0 = blockIdx.y * 128;
  int srow = tid >> 2;            // staging source row (site 0)
  int scol = (tid & 3) * 8;       // staging source col
  int wbase = w * 1024;           // wave's byte chunk within a 4KB site
  const bf16* Ab = A + (size_t)r0 * K;
  const bf16* Bb = Bw + (size_t)c0 * K;
  f32x4 acc[4][4] = {};
  for (int k0 = 0; k0 < K; k0 += 32) {
    gl_lds16(Ab + (size_t)srow * K + k0 + scol, (char*)As + wbase);
    gl_lds16(Ab + (size_t)(srow + 64) * K + k0 + scol, (char*)As + 4096 + wbase);
    gl_lds16(Bb + (size_t)srow * K + k0 + scol, (char*)Bs + wbase);
    gl_lds16(Bb + (size_t)(srow + 64) * K + k0 + scol, (char*)Bs + 4096 + wbase);
    __syncthreads();
    bf16x8 af[4], bfr[4];
#pragma unroll
    for (int i = 0; i < 4; ++i) {
      __builtin_memcpy(&af[i], As + (wr + i * 16 + lr) * 32 + lg * 8, 16);
      __builtin_memcpy(&bfr[i], Bs + (wc + i * 16 + lr) * 32 + lg * 8, 16);
    }
#pragma unroll
    for (int i = 0; i < 4; ++i)
#pragma unroll
      for (int j = 0; j < 4; ++j)
        acc[i][j] = __builtin_amdgcn_mfma_f32_16x16x32_bf16(af[i], bfr[j], acc[i][j], 0, 0, 0);
    __syncthreads();
  }
  // epilogue: D row = (lg*4 + reg), col = lr  [m89-verified layout]
#pragma unroll
  for (int i = 0; i < 4; ++i)
#pragma unroll
    for (int j = 0; j < 4; ++j) {
      int orow = r0 + wr + i * 16 + lg * 4;
      int ocol = c0 + wc + j * 16 + lr;
      if (EPI == 0) {
        bf16* C = (bf16*)Cout;
#pragma unroll
        for (int jr = 0; jr < 4; ++jr)
          C[(size_t)(orow + jr) * N + ocol] = (bf16)acc[i][j][jr];
      } else {
        float* C = (float*)Cout;
#pragma unroll
        for (int jr = 0; jr < 4; ++jr)
          C[(size_t)(orow + jr) * N + ocol] = acc[i][j][jr];
      }
    }
}

// ---------------- RoPE in-place on row-major [B*S][H] bf16 ----------------
// pair (i, i+64) within each head; Q additionally scaled by log2(e)/sqrt(128).
__global__ __launch_bounds__(256) void rope_kernel(bf16* __restrict__ X,
                                                   const int* __restrict__ pos,
                                                   float scale) {
  int r = blockIdx.x;  // b*S + s
  float pf = (float)pos[r];
  int i = threadIdx.x & 63;
  int h0 = threadIdx.x >> 6;
  // inv_freq = 10000^(-i/64) = exp2(-i * log2(10000)/64)
  float ang = pf * exp2f(-0.20762050593046868f * (float)i);
  float sn = sinf(ang), cs = cosf(ang);
  bf16* row = X + (size_t)r * H_;
#pragma unroll
  for (int h = h0; h < NH; h += 4) {
    bf16* p = row + h * HD + i;
    float a = (float)p[0], b = (float)p[64];
    p[0] = (bf16)((a * cs - b * sn) * scale);
    p[64] = (bf16)((b * cs + a * sn) * scale);
  }
}

// ---------------- V transpose: [b,s,h,d] row-major -> Vt[b,h,d,s] ----------------
__global__ __launch_bounds__(256) void transpose_v(const bf16* __restrict__ V,
                                                   bf16* __restrict__ Vt) {
  __shared__ __attribute__((aligned(16))) bf16 tile[64][130];
  int bh = blockIdx.y;  // b*NH + h
  int b = bh >> 5, h = bh & 31;
  int s0 = blockIdx.x * 64;
  int t = threadIdx.x;
  const bf16* src = V + (size_t)(b * S_ + s0) * H_ + h * HD;
  int rr = t >> 4, cc = (t & 15) * 8;
#pragma unroll
  for (int k = 0; k < 4; ++k) {
    bf16x8 v;
    __builtin_memcpy(&v, src + (size_t)(rr + k * 16) * H_ + cc, 16);
#pragma unroll
    for (int u = 0; u < 8; ++u) tile[rr + k * 16][cc + u] = v[u];
  }
  __syncthreads();
  bf16* dst = Vt + (size_t)bh * HD * S_;
  int sl = t & 63, d0 = t >> 6;
  for (int j = 0; j < 32; ++j) {
    int d = d0 + j * 4;
    dst[(size_t)d * S_ + s0 + sl] = tile[sl][d];
  }
}

// ---------------- causal flash attention ----------------
// Q,K row-major bf16 [B*S][H] (RoPE'd; Q pre-scaled by log2e/sqrt(hd)).
// Vt [B*NH][HD][S].  Out bf16 row-major [B*S][H].
__global__ __launch_bounds__(256) void attn_kernel(const bf16* __restrict__ Q,
                                                   const bf16* __restrict__ Km,
                                                   const bf16* __restrict__ Vt,
                                                   bf16* __restrict__ Out) {
  __shared__ __attribute__((aligned(16))) bf16 P_lds[4][16][32];
  int w = threadIdx.x >> 6, l = threadIdx.x & 63;
  int lr = l & 15, lg = l >> 4;
  int bh = blockIdx.y, b = bh >> 5, h = bh & 31;
  int q0 = blockIdx.x * 64 + w * 16;
  const bf16* Qb = Q + (size_t)b * S_ * H_ + h * HD;
  const bf16* Kb = Km + (size_t)b * S_ * H_ + h * HD;
  const bf16* Vb = Vt + (size_t)bh * HD * S_;
  bf16x8 qf[4];
#pragma unroll
  for (int dk = 0; dk < 4; ++dk)
    __builtin_memcpy(&qf[dk], Qb + (size_t)(q0 + lr) * H_ + dk * 32 + lg * 8, 16);
  f32x4 o[8] = {};
  float m[4] = {-INFINITY, -INFINITY, -INFINITY, -INFINITY};
  float ls[4] = {0.f, 0.f, 0.f, 0.f};
  int nblk = (q0 + 47) >> 5;  // KV blocks of 32 covering rows <= q0+15
  for (int blk = 0; blk < nblk; ++blk) {
    int kv0 = blk * 32;
    f32x4 s0 = {}, s1 = {};
#pragma unroll
    for (int dk = 0; dk < 4; ++dk) {
      bf16x8 kf0, kf1;
      __builtin_memcpy(&kf0, Kb + (size_t)(kv0 + lr) * H_ + dk * 32 + lg * 8, 16);
      __builtin_memcpy(&kf1, Kb + (size_t)(kv0 + 16 + lr) * H_ + dk * 32 + lg * 8, 16);
      s0 = __builtin_amdgcn_mfma_f32_16x16x32_bf16(qf[dk], kf0, s0, 0, 0, 0);
      s1 = __builtin_amdgcn_mfma_f32_16x16x32_bf16(qf[dk], kf1, s1, 0, 0, 0);
    }
    if (kv0 + 31 > q0) {  // diagonal block: causal mask
#pragma unroll
      for (int j = 0; j < 4; ++j) {
        int qg = q0 + lg * 4 + j;
        if (kv0 + lr > qg) s0[j] = -INFINITY;
        if (kv0 + 16 + lr > qg) s1[j] = -INFINITY;
      }
    }
    float sc[4], p0[4], p1[4];
#pragma unroll
    for (int j = 0; j < 4; ++j) {
      float mx = fmaxf(s0[j], s1[j]);
      mx = fmaxf(mx, __shfl_xor(mx, 1));
      mx = fmaxf(mx, __shfl_xor(mx, 2));
      mx = fmaxf(mx, __shfl_xor(mx, 4));
      mx = fmaxf(mx, __shfl_xor(mx, 8));
      float mn = fmaxf(m[j], mx);
      sc[j] = exp2f(m[j] - mn);
      m[j] = mn;
      p0[j] = exp2f(s0[j] - mn);
      p1[j] = exp2f(s1[j] - mn);
      float rs = p0[j] + p1[j];
      rs += __shfl_xor(rs, 1);
      rs += __shfl_xor(rs, 2);
      rs += __shfl_xor(rs, 4);
      rs += __shfl_xor(rs, 8);
      ls[j] = ls[j] * sc[j] + rs;
    }
#pragma unroll
    for (int dt = 0; dt < 8; ++dt)
#pragma unroll
      for (int j = 0; j < 4; ++j) o[dt][j] *= sc[j];
    // P: C-layout -> LDS -> A-layout (per-wave region, same-wave DS ordering)
#pragma unroll
    for (int j = 0; j < 4; ++j) {
      P_lds[w][lg * 4 + j][lr] = (bf16)p0[j];
      P_lds[w][lg * 4 + j][16 + lr] = (bf16)p1[j];
    }
    bf16x8 pa;
    __builtin_memcpy(&pa, &P_lds[w][lr][lg * 8], 16);
#pragma unroll
    for (int dt = 0; dt < 8; ++dt) {
      bf16x8 vf;
      __builtin_memcpy(&vf, Vb + (size_t)(dt * 16 + lr) * S_ + kv0 + lg * 8, 16);
      o[dt] = __builtin_amdgcn_mfma_f32_16x16x32_bf16(pa, vf, o[dt], 0, 0, 0);
    }
  }
  bf16* Ob = Out + (size_t)b * S_ * H_ + h * HD;
#pragma unroll
  for (int j = 0; j < 4; ++j) {
    float inv = 1.0f / ls[j];
#pragma unroll
    for (int dt = 0; dt < 8; ++dt)
      Ob[(size_t)(q0 + lg * 4 + j) * H_ + dt * 16 + lr] = (bf16)(o[dt][j] * inv);
  }
}

extern "C" void kernel_launch(void* const* d_in, const int* in_sizes, int n_in,
                              void* d_out, int out_size, void* d_ws, size_t ws_size,
                              hipStream_t stream) {
  const float* X = (const float*)d_in[0];
  // d_in[1] = attention_mask: provably causal for this problem -> handled analytically
  const int* pos = (const int*)d_in[2];
  const float* Wq = (const float*)d_in[3];
  const float* Wk = (const float*)d_in[4];
  const float* Wv = (const float*)d_in[5];
  const float* Wo = (const float*)d_in[6];
  float* out = (float*)d_out;
  char* ws = (char*)d_ws;
  const size_t MB32 = 32ull << 20;
  bf16* Xb = (bf16*)ws;               // X bf16; later reused as attention output
  bf16* Wb = (bf16*)(ws + MB32);      // current weight bf16
  bf16* Qb = (bf16*)(ws + 2 * MB32);
  bf16* Kb = (bf16*)(ws + 3 * MB32);
  bf16* Vb = (bf16*)(ws + 4 * MB32);
  bf16* Vt = (bf16*)(ws + 5 * MB32);

  const int n4 = (4096 * 4096) / 4;
  dim3 cgrid(n4 / 256), cblk(256);
  dim3 ggrid(32, 32), gblk(256);

  cast_kernel<<<cgrid, cblk, 0, stream>>>(X, Xb, n4);
  cast_kernel<<<cgrid, cblk, 0, stream>>>(Wq, Wb, n4);
  gemm_bt<0><<<ggrid, gblk, 0, stream>>>(Xb, Wb, Qb);
  cast_kernel<<<cgrid, cblk, 0, stream>>>(Wk, Wb, n4);
  gemm_bt<0><<<ggrid, gblk, 0, stream>>>(Xb, Wb, Kb);
  cast_kernel<<<cgrid, cblk, 0, stream>>>(Wv, Wb, n4);
  gemm_bt<0><<<ggrid, gblk, 0, stream>>>(Xb, Wb, Vb);

  const float qscale = 1.4426950408889634f / 11.313708498984760f;  // log2(e)/sqrt(128)
  rope_kernel<<<dim3(4096), 256, 0, stream>>>(Qb, pos, qscale);
  rope_kernel<<<dim3(4096), 256, 0, stream>>>(Kb, pos, 1.0f);
  transpose_v<<<dim3(32, 64), 256, 0, stream>>>(Vb, Vt);

  attn_kernel<<<dim3(32, 64), 256, 0, stream>>>(Qb, Kb, Vt, Xb);

  cast_kernel<<<cgrid, cblk, 0, stream>>>(Wo, Wb, n4);
  gemm_bt<1><<<ggrid, gblk, 0, stream>>>(Xb, Wb, out);
}

// Round 2
// 1215.909 us; speedup vs baseline: 1.5337x; 1.5337x over previous
//
#include <hip/hip_runtime.h>
#include <cstdint>
#include <cmath>

typedef __bf16 bf16;
typedef __bf16 bf16x8 __attribute__((ext_vector_type(8)));
typedef __bf16 bf16x4 __attribute__((ext_vector_type(4)));
typedef float f32x4 __attribute__((ext_vector_type(4)));

#define B_ 2
#define S_ 2048
#define H_ 4096
#define NH 32
#define HD 128

__device__ __forceinline__ void gl_lds16(const void* g, void* l) {
  __builtin_amdgcn_global_load_lds(
      (const __attribute__((address_space(1))) unsigned int*)g,
      (__attribute__((address_space(3))) unsigned int*)l, 16, 0, 0);
}

// ---------------- cast f32 -> bf16 (x4 vectorized) ----------------
__global__ __launch_bounds__(256) void cast_kernel(const float* __restrict__ in,
                                                   bf16* __restrict__ out, int n4) {
  int i = blockIdx.x * 256 + threadIdx.x;
  if (i < n4) {
    float4 v = ((const float4*)in)[i];
    bf16x4 o = {(bf16)v.x, (bf16)v.y, (bf16)v.z, (bf16)v.w};
    ((bf16x4*)out)[i] = o;
  }
}

// ---------------- GEMM: C[M,N] = A[M,K] * B[N,K]^T, M=N=K=4096 ----------------
template <int EPI>
__global__ __launch_bounds__(256) void gemm_bt(const bf16* __restrict__ A,
                                               const bf16* __restrict__ Bw,
                                               void* __restrict__ Cout) {
  constexpr int K = 4096, N = 4096;
  __shared__ __attribute__((aligned(16))) bf16 As[128 * 32];
  __shared__ __attribute__((aligned(16))) bf16 Bs[128 * 32];
  int tid = threadIdx.x;
  int l = tid & 63;
  int lr = l & 15, lg = l >> 4;
  int w = tid >> 6;
  int wr = (w >> 1) * 64, wc = (w & 1) * 64;
  int r0 = blockIdx.x * 128, c0 = blockIdx.y * 128;
  int srow = tid >> 2;
  int scol = (tid & 3) * 8;
  int wbase = w * 1024;
  const bf16* Ab = A + (size_t)r0 * K;
  const bf16* Bb = Bw + (size_t)c0 * K;
  f32x4 acc[4][4] = {};
  for (int k0 = 0; k0 < K; k0 += 32) {
    gl_lds16(Ab + (size_t)srow * K + k0 + scol, (char*)As + wbase);
    gl_lds16(Ab + (size_t)(srow + 64) * K + k0 + scol, (char*)As + 4096 + wbase);
    gl_lds16(Bb + (size_t)srow * K + k0 + scol, (char*)Bs + wbase);
    gl_lds16(Bb + (size_t)(srow + 64) * K + k0 + scol, (char*)Bs + 4096 + wbase);
    __syncthreads();
    bf16x8 af[4], bfr[4];
#pragma unroll
    for (int i = 0; i < 4; ++i) {
      __builtin_memcpy(&af[i], As + (wr + i * 16 + lr) * 32 + lg * 8, 16);
      __builtin_memcpy(&bfr[i], Bs + (wc + i * 16 + lr) * 32 + lg * 8, 16);
    }
#pragma unroll
    for (int i = 0; i < 4; ++i)
#pragma unroll
      for (int j = 0; j < 4; ++j)
        acc[i][j] = __builtin_amdgcn_mfma_f32_16x16x32_bf16(af[i], bfr[j], acc[i][j], 0, 0, 0);
    __syncthreads();
  }
#pragma unroll
  for (int i = 0; i < 4; ++i)
#pragma unroll
    for (int j = 0; j < 4; ++j) {
      int orow = r0 + wr + i * 16 + lg * 4;
      int ocol = c0 + wc + j * 16 + lr;
      if (EPI == 0) {
        bf16* C = (bf16*)Cout;
#pragma unroll
        for (int jr = 0; jr < 4; ++jr)
          C[(size_t)(orow + jr) * N + ocol] = (bf16)acc[i][j][jr];
      } else {
        float* C = (float*)Cout;
#pragma unroll
        for (int jr = 0; jr < 4; ++jr)
          C[(size_t)(orow + jr) * N + ocol] = acc[i][j][jr];
      }
    }
}

// ---------------- RoPE in-place on row-major [B*S][H] bf16 ----------------
__global__ __launch_bounds__(256) void rope_kernel(bf16* __restrict__ X,
                                                   const int* __restrict__ pos,
                                                   float scale) {
  int r = blockIdx.x;
  float pf = (float)pos[r];
  int i = threadIdx.x & 63;
  int h0 = threadIdx.x >> 6;
  float ang = pf * exp2f(-0.20762050593046868f * (float)i);
  float sn = sinf(ang), cs = cosf(ang);
  bf16* row = X + (size_t)r * H_;
#pragma unroll
  for (int h = h0; h < NH; h += 4) {
    bf16* p = row + h * HD + i;
    float a = (float)p[0], b = (float)p[64];
    p[0] = (bf16)((a * cs - b * sn) * scale);
    p[64] = (bf16)((b * cs + a * sn) * scale);
  }
}

// ---------------- V transpose: [b,s,h,d] -> Vt[b,h,d,s] ----------------
__global__ __launch_bounds__(256) void transpose_v(const bf16* __restrict__ V,
                                                   bf16* __restrict__ Vt) {
  __shared__ __attribute__((aligned(16))) bf16 tile[64][130];
  int bh = blockIdx.y;
  int b = bh >> 5, h = bh & 31;
  int s0 = blockIdx.x * 64;
  int t = threadIdx.x;
  const bf16* src = V + (size_t)(b * S_ + s0) * H_ + h * HD;
  int rr = t >> 4, cc = (t & 15) * 8;
#pragma unroll
  for (int k = 0; k < 4; ++k) {
    bf16x8 v;
    __builtin_memcpy(&v, src + (size_t)(rr + k * 16) * H_ + cc, 16);
#pragma unroll
    for (int u = 0; u < 8; ++u) tile[rr + k * 16][cc + u] = v[u];
  }
  __syncthreads();
  bf16* dst = Vt + (size_t)bh * HD * S_;
  int sl = t & 63, d0 = t >> 6;
  for (int j = 0; j < 32; ++j) {
    int d = d0 + j * 4;
    dst[(size_t)d * S_ + s0 + sl] = tile[sl][d];
  }
}

// ---------------- causal flash attention (LDS-staged, double-buffered) ----------------
// Q,K row-major bf16 [B*S][H] (Q pre-scaled by log2e/sqrt(hd)). Vt [B*NH][HD][S].
// Block: 4 waves x 16 q-rows = 64 q-rows; KV tile = 64; heavy-first qt mapping.
__global__ __launch_bounds__(256) void attn_kernel(const bf16* __restrict__ Q,
                                                   const bf16* __restrict__ Km,
                                                   const bf16* __restrict__ Vt,
                                                   bf16* __restrict__ Out) {
  __shared__ __attribute__((aligned(16))) bf16 Ks[2][64 * 128];   // [kv][d] swizzled
  __shared__ __attribute__((aligned(16))) bf16 Vs[2][128 * 64];   // [d][kv] swizzled
  __shared__ __attribute__((aligned(16))) bf16 P_lds[4][16 * 64]; // per-wave, swizzled
  int tid = threadIdx.x;
  int w = tid >> 6, l = tid & 63;
  int lr = l & 15, lg = l >> 4;
  int bh = blockIdx.y, b = bh >> 5, h = bh & 31;
  int qt = 31 - (int)blockIdx.x;  // heavy tiles dispatch first
  int q0w = qt * 64 + w * 16;
  const bf16* Qb = Q + (size_t)b * S_ * H_ + h * HD;
  const char* Kg = (const char*)(Km + (size_t)b * S_ * H_ + h * HD);
  const char* Vg = (const char*)(Vt + (size_t)bh * HD * S_);
  bf16* Ob = Out + (size_t)b * S_ * H_ + h * HD;

  bf16x8 qf[4];
#pragma unroll
  for (int dk = 0; dk < 4; ++dk)
    __builtin_memcpy(&qf[dk], Qb + (size_t)(q0w + lr) * H_ + dk * 32 + lg * 8, 16);

  f32x4 o[8] = {};
  float m[4] = {-INFINITY, -INFINITY, -INFINITY, -INFINITY};
  float ls[4] = {0.f, 0.f, 0.f, 0.f};

  int nkv = qt + 1;  // KV tiles of 64 covering rows <= qt*64+63

  // stage K tile: 64 rows x 256B; 4 passes, wave-uniform LDS chunk + pre-swizzled src
  auto stageK = [&](int buf, int kv0) {
#pragma unroll
    for (int p = 0; p < 4; ++p) {
      int row = p * 16 + (tid >> 4);
      int src = ((tid & 15) * 16) ^ ((row & 7) << 4);
      gl_lds16(Kg + (size_t)(kv0 + row) * (H_ * 2) + src,
               (char*)&Ks[buf][0] + p * 4096 + w * 1024);
    }
  };
  // stage V tile: 128 rows x 128B; 4 passes
  auto stageV = [&](int buf, int kv0) {
#pragma unroll
    for (int p = 0; p < 4; ++p) {
      int row = p * 32 + (tid >> 3);
      int src = ((tid & 7) * 16) ^ ((row & 7) << 4);
      gl_lds16(Vg + (size_t)row * (S_ * 2) + (size_t)kv0 * 2 + src,
               (char*)&Vs[buf][0] + p * 4096 + w * 1024);
    }
  };

  stageK(0, 0);
  stageV(0, 0);
  __syncthreads();

  int cur = 0;
  char* Pl = (char*)&P_lds[w][0];
  for (int t = 0; t < nkv; ++t) {
    int kv0 = t * 64;
    if (t + 1 < nkv) {  // prefetch next tile into other buffer (stays in flight)
      stageK(cur ^ 1, kv0 + 64);
      stageV(cur ^ 1, kv0 + 64);
    }
    const char* Kl = (const char*)&Ks[cur][0];
    const char* Vl = (const char*)&Vs[cur][0];
    // ---- QK^T ----
    f32x4 s4[4] = {};
#pragma unroll
    for (int dk = 0; dk < 4; ++dk)
#pragma unroll
      for (int st = 0; st < 4; ++st) {
        int row = st * 16 + lr;
        int cb = (dk * 64 + lg * 16) ^ ((row & 7) << 4);
        bf16x8 kf;
        __builtin_memcpy(&kf, Kl + row * 256 + cb, 16);
        s4[st] = __builtin_amdgcn_mfma_f32_16x16x32_bf16(qf[dk], kf, s4[st], 0, 0, 0);
      }
    // ---- causal mask (only last tile touches the diagonal) ----
    if (t == nkv - 1) {
#pragma unroll
      for (int st = 0; st < 4; ++st)
#pragma unroll
        for (int j = 0; j < 4; ++j) {
          int kv = kv0 + st * 16 + lr;
          int qg = q0w + lg * 4 + j;
          if (kv > qg) s4[st][j] = -INFINITY;
        }
    }
    // ---- online softmax (wave-parallel, 16-lane groups) ----
    float pv[4][4], scj[4];
#pragma unroll
    for (int j = 0; j < 4; ++j) {
      float mx = fmaxf(fmaxf(s4[0][j], s4[1][j]), fmaxf(s4[2][j], s4[3][j]));
      mx = fmaxf(mx, __shfl_xor(mx, 1));
      mx = fmaxf(mx, __shfl_xor(mx, 2));
      mx = fmaxf(mx, __shfl_xor(mx, 4));
      mx = fmaxf(mx, __shfl_xor(mx, 8));
      float mn = fmaxf(m[j], mx);
      scj[j] = exp2f(m[j] - mn);
      m[j] = mn;
      float rs = 0.f;
#pragma unroll
      for (int st = 0; st < 4; ++st) {
        pv[st][j] = exp2f(s4[st][j] - mn);
        rs += pv[st][j];
      }
      rs += __shfl_xor(rs, 1);
      rs += __shfl_xor(rs, 2);
      rs += __shfl_xor(rs, 4);
      rs += __shfl_xor(rs, 8);
      ls[j] = ls[j] * scj[j] + rs;
    }
#pragma unroll
    for (int dt = 0; dt < 8; ++dt)
#pragma unroll
      for (int j = 0; j < 4; ++j) o[dt][j] *= scj[j];
    // ---- P: C-layout -> LDS (swizzled) -> A-layout ----
#pragma unroll
    for (int st = 0; st < 4; ++st)
#pragma unroll
      for (int j = 0; j < 4; ++j) {
        int row = lg * 4 + j;
        int cb = ((st * 16 + lr) * 2) ^ ((row & 7) << 4);
        *(bf16*)(Pl + row * 128 + cb) = (bf16)pv[st][j];
      }
    bf16x8 pa[2];
#pragma unroll
    for (int ks = 0; ks < 2; ++ks) {
      int cb = (ks * 64 + lg * 16) ^ ((lr & 7) << 4);
      __builtin_memcpy(&pa[ks], Pl + lr * 128 + cb, 16);
    }
    // ---- PV ----
#pragma unroll
    for (int dt = 0; dt < 8; ++dt)
#pragma unroll
      for (int ks = 0; ks < 2; ++ks) {
        int row = dt * 16 + lr;
        int cb = (ks * 64 + lg * 16) ^ ((row & 7) << 4);
        bf16x8 vf;
        __builtin_memcpy(&vf, Vl + row * 128 + cb, 16);
        o[dt] = __builtin_amdgcn_mfma_f32_16x16x32_bf16(pa[ks], vf, o[dt], 0, 0, 0);
      }
    __syncthreads();  // drains prefetch vmcnt + publishes next buffer
    cur ^= 1;
  }
#pragma unroll
  for (int j = 0; j < 4; ++j) {
    float inv = 1.0f / ls[j];
#pragma unroll
    for (int dt = 0; dt < 8; ++dt)
      Ob[(size_t)(q0w + lg * 4 + j) * H_ + dt * 16 + lr] = (bf16)(o[dt][j] * inv);
  }
}

extern "C" void kernel_launch(void* const* d_in, const int* in_sizes, int n_in,
                              void* d_out, int out_size, void* d_ws, size_t ws_size,
                              hipStream_t stream) {
  const float* X = (const float*)d_in[0];
  const int* pos = (const int*)d_in[2];
  const float* Wq = (const float*)d_in[3];
  const float* Wk = (const float*)d_in[4];
  const float* Wv = (const float*)d_in[5];
  const float* Wo = (const float*)d_in[6];
  float* out = (float*)d_out;
  char* ws = (char*)d_ws;
  const size_t MB32 = 32ull << 20;
  bf16* Xb = (bf16*)ws;
  bf16* Wb = (bf16*)(ws + MB32);
  bf16* Qb = (bf16*)(ws + 2 * MB32);
  bf16* Kb = (bf16*)(ws + 3 * MB32);
  bf16* Vb = (bf16*)(ws + 4 * MB32);
  bf16* Vt = (bf16*)(ws + 5 * MB32);

  const int n4 = (4096 * 4096) / 4;
  dim3 cgrid(n4 / 256), cblk(256);
  dim3 ggrid(32, 32), gblk(256);

  cast_kernel<<<cgrid, cblk, 0, stream>>>(X, Xb, n4);
  cast_kernel<<<cgrid, cblk, 0, stream>>>(Wq, Wb, n4);
  gemm_bt<0><<<ggrid, gblk, 0, stream>>>(Xb, Wb, Qb);
  cast_kernel<<<cgrid, cblk, 0, stream>>>(Wk, Wb, n4);
  gemm_bt<0><<<ggrid, gblk, 0, stream>>>(Xb, Wb, Kb);
  cast_kernel<<<cgrid, cblk, 0, stream>>>(Wv, Wb, n4);
  gemm_bt<0><<<ggrid, gblk, 0, stream>>>(Xb, Wb, Vb);

  const float qscale = 1.4426950408889634f / 11.313708498984760f;  // log2(e)/sqrt(128)
  rope_kernel<<<dim3(4096), 256, 0, stream>>>(Qb, pos, qscale);
  rope_kernel<<<dim3(4096), 256, 0, stream>>>(Kb, pos, 1.0f);
  transpose_v<<<dim3(32, 64), 256, 0, stream>>>(Vb, Vt);

  attn_kernel<<<dim3(32, 64), 256, 0, stream>>>(Qb, Kb, Vt, Xb);

  cast_kernel<<<cgrid, cblk, 0, stream>>>(Wo, Wb, n4);
  gemm_bt<1><<<ggrid, gblk, 0, stream>>>(Xb, Wb, out);
}